// Round 1
// baseline (861.050 us; speedup 1.0000x reference)
//
#include <hip/hip_runtime.h>
#include <math.h>

// GptOssRouter: T=16384 tokens, H=2880 hidden, E=128 experts, top-K=4.
// logits = x @ W^T + bias; top-4 softmax scattered into [T,E]; plus indices.
// Strategy: fp32 GEMM for candidate selection (top-8), fp64 re-accumulation of
// the 8 candidates so the top-4 ORDER matches the float64 numpy reference
// (the absmax threshold on indices makes ordering flips fatal).

#define T_TOK 16384
#define HDIM  2880
#define EEXP  128
#define KTOP  4
#define TPB   32      // tokens per block
#define KC    288     // K-chunk staged in LDS (2880 = 10 * 288)
#define NTHR  256

__global__ __launch_bounds__(NTHR) void router_kernel(
    const float* __restrict__ x, const float* __restrict__ w,
    const float* __restrict__ bias, float* __restrict__ out)
{
    __shared__ float  x_lds[TPB * KC];        // 36 KB
    __shared__ float  logits_lds[TPB * EEXP]; // 16 KB (reused for scores)
    __shared__ double cand_val[TPB * 8];      // 2 KB
    __shared__ int    cand_idx[TPB * 8];      // 1 KB

    const int tid  = threadIdx.x;
    const int tok0 = blockIdx.x * TPB;

    // ---------------- Phase A: fp32 logits, 4 tokens x 4 experts / thread ---
    const int eg = tid & 31;   // expert group 0..31
    const int tg = tid >> 5;   // token group 0..7
    const int e0 = eg * 4;
    const int t0 = tg * 4;

    float acc[4][4];
#pragma unroll
    for (int t = 0; t < 4; ++t)
#pragma unroll
        for (int e = 0; e < 4; ++e) acc[t][e] = 0.f;

    for (int k0 = 0; k0 < HDIM; k0 += KC) {
        __syncthreads();
        // cooperative stage of x[tok0..tok0+31][k0..k0+KC) : 2304 float4, 9/thread
#pragma unroll
        for (int i = 0; i < (TPB * KC / 4) / NTHR; ++i) {
            int f   = tid + i * NTHR;
            int tok = f / (KC / 4);
            int c4  = f % (KC / 4);
            ((float4*)x_lds)[tok * (KC / 4) + c4] =
                *((const float4*)(x + (size_t)(tok0 + tok) * HDIM + k0) + c4);
        }
        __syncthreads();

        for (int kk = 0; kk < KC; kk += 4) {
            float4 xv[4];
#pragma unroll
            for (int t = 0; t < 4; ++t)
                xv[t] = *(const float4*)&x_lds[(t0 + t) * KC + kk];
#pragma unroll
            for (int e = 0; e < 4; ++e) {
                float4 wv = *(const float4*)(w + (size_t)(e0 + e) * HDIM + k0 + kk);
#pragma unroll
                for (int t = 0; t < 4; ++t) {
                    acc[t][e] = fmaf(xv[t].x, wv.x, acc[t][e]);
                    acc[t][e] = fmaf(xv[t].y, wv.y, acc[t][e]);
                    acc[t][e] = fmaf(xv[t].z, wv.z, acc[t][e]);
                    acc[t][e] = fmaf(xv[t].w, wv.w, acc[t][e]);
                }
            }
        }
    }

#pragma unroll
    for (int t = 0; t < 4; ++t)
#pragma unroll
        for (int e = 0; e < 4; ++e)
            logits_lds[(t0 + t) * EEXP + e0 + e] = acc[t][e] + bias[e0 + e];
    __syncthreads();

    // ---------------- top-8 candidate selection per token (fp32) ------------
    if (tid < TPB) {
        float v[8]; int id[8];
#pragma unroll
        for (int j = 0; j < 8; ++j) { v[j] = -3.4e38f; id[j] = 0x7fffffff; }
        for (int e = 0; e < EEXP; ++e) {
            float lv = logits_lds[tid * EEXP + e];
            if (lv > v[7]) {
                int j = 7;
                while (j > 0 && v[j - 1] < lv) {
                    v[j] = v[j - 1]; id[j] = id[j - 1]; --j;
                }
                v[j] = lv; id[j] = e;
            }
        }
#pragma unroll
        for (int j = 0; j < 8; ++j) cand_idx[tid * 8 + j] = id[j];
    }
    __syncthreads();

    // ---------------- Phase B: fp64 re-accumulation of 8 candidates ---------
    const int tt = tid >> 3;   // token 0..31
    const int cc = tid & 7;    // candidate 0..7
    const int ce = cand_idx[tt * 8 + cc];
    double accd = 0.0;
    for (int k0 = 0; k0 < HDIM; k0 += KC) {
        __syncthreads();
#pragma unroll
        for (int i = 0; i < (TPB * KC / 4) / NTHR; ++i) {
            int f   = tid + i * NTHR;
            int tok = f / (KC / 4);
            int c4  = f % (KC / 4);
            ((float4*)x_lds)[tok * (KC / 4) + c4] =
                *((const float4*)(x + (size_t)(tok0 + tok) * HDIM + k0) + c4);
        }
        __syncthreads();
        const float* wp = w + (size_t)ce * HDIM + k0;
        for (int kk = 0; kk < KC; kk += 4) {
            float4 wv = *(const float4*)(wp + kk);
            float4 xv = *(const float4*)&x_lds[tt * KC + kk];
            accd = fma((double)xv.x, (double)wv.x, accd);
            accd = fma((double)xv.y, (double)wv.y, accd);
            accd = fma((double)xv.z, (double)wv.z, accd);
            accd = fma((double)xv.w, (double)wv.w, accd);
        }
    }
    accd += (double)bias[ce];
    cand_val[tt * 8 + cc] = accd;
    __syncthreads();

    // ---------------- top-4 sort, softmax, outputs ---------------------------
    float* score_lds = logits_lds;  // logits dead; reuse as dense score tile
    for (int i = tid; i < TPB * EEXP; i += NTHR) score_lds[i] = 0.f;

    double sv[8]; int sid[8]; double ev[4]; double invs = 0.0;
    if (tid < TPB) {
#pragma unroll
        for (int c = 0; c < 8; ++c) {
            sv[c] = cand_val[tid * 8 + c];
            sid[c] = cand_idx[tid * 8 + c];
        }
        // selection sort of top-4, descending, stable (lower index on tie)
        for (int j = 0; j < 4; ++j) {
            int b = j;
            for (int c = j + 1; c < 8; ++c)
                if (sv[c] > sv[b] || (sv[c] == sv[b] && sid[c] < sid[b])) b = c;
            double tv = sv[j]; sv[j] = sv[b]; sv[b] = tv;
            int ti = sid[j]; sid[j] = sid[b]; sid[b] = ti;
        }
        double m = sv[0], s = 0.0;
#pragma unroll
        for (int j = 0; j < 4; ++j) { ev[j] = exp(sv[j] - m); s += ev[j]; }
        invs = 1.0 / s;
        // indices output (read back as float32 by the harness)
        float* oidx = out + (size_t)T_TOK * EEXP;
#pragma unroll
        for (int j = 0; j < 4; ++j)
            oidx[(size_t)(tok0 + tid) * KTOP + j] = (float)sid[j];
    }
    __syncthreads();
    if (tid < TPB) {
#pragma unroll
        for (int j = 0; j < 4; ++j)
            score_lds[tid * EEXP + sid[j]] = (float)(ev[j] * invs);
    }
    __syncthreads();

    float4* outv = (float4*)(out + (size_t)tok0 * EEXP);
    for (int i = tid; i < TPB * EEXP / 4; i += NTHR)
        outv[i] = ((float4*)score_lds)[i];
}

extern "C" void kernel_launch(void* const* d_in, const int* in_sizes, int n_in,
                              void* d_out, int out_size, void* d_ws, size_t ws_size,
                              hipStream_t stream) {
    const float* x    = (const float*)d_in[0];
    const float* w    = (const float*)d_in[1];
    const float* bias = (const float*)d_in[2];
    float* out        = (float*)d_out;

    dim3 grid(T_TOK / TPB), block(NTHR);
    hipLaunchKernelGGL(router_kernel, grid, block, 0, stream, x, w, bias, out);
}

// Round 3
// 388.324 us; speedup vs baseline: 2.2173x; 2.2173x over previous
//
#include <hip/hip_runtime.h>
#include <math.h>

// GptOssRouter: T=16384, H=2880, E=128, K=4.
// Phase A: bf16 MFMA GEMM (x@W^T+bias) -> fp32 logits (error ~4e-3, plenty to
//          isolate the true top-4 inside the measured top-8).
// Phase B: fp64 re-accumulation of the 8 candidates so top-4 ORDER matches the
//          float64 numpy reference exactly (index flips are fatal).

#define T_TOK 16384
#define HDIM  2880
#define EEXP  128
#define KTOP  4
#define TM    32            // tokens per block
#define NTHR  256           // 4 waves
#define KC    96            // K-chunk (2880 = 30*96), 3 MFMA k-steps of 32
#define LDROW 208           // bf16 LDS row stride in BYTES (104 bf16, 13*16B)
#define LSTR  132           // logits LDS stride (floats)
#define XBSTR 100           // phase-B x LDS stride (floats)

#define XA_OFF    0
#define WA_OFF    (TM * LDROW)                    // 6656
#define CAND_OFF  (WA_OFF + EEXP * LDROW)         // 33280
#define CANDV_OFF (CAND_OFF + TM * 8 * 4)         // 34304
#define SMEM_SIZE (CANDV_OFF + TM * 8 * 8)        // 36352 bytes

typedef __attribute__((ext_vector_type(8))) short bf16x8;
typedef __attribute__((ext_vector_type(4))) float f32x4;

static __device__ __forceinline__ unsigned short f2bf(float f) {
    union { float f; unsigned int u; } v; v.f = f;
    unsigned int u = v.u;
    return (unsigned short)((u + 0x7fffu + ((u >> 16) & 1u)) >> 16);  // RNE
}

__global__ __launch_bounds__(NTHR, 2) void router_kernel(
    const float* __restrict__ x, const float* __restrict__ w,
    const float* __restrict__ bias, float* __restrict__ out)
{
    __shared__ char smem[SMEM_SIZE];
    const int tid  = threadIdx.x;
    const int tok0 = blockIdx.x * TM;
    const int lane = tid & 63;
    const int wave = tid >> 6;
    const int wt   = wave & 1;          // token 16-row group
    const int we   = wave >> 1;         // expert 64-col group
    const int r    = lane & 15;
    const int g    = lane >> 4;

    char* xA = smem + XA_OFF;
    char* wA = smem + WA_OFF;

    // ---------------- Phase A: bf16 MFMA GEMM --------------------------------
    f32x4 acc[4];
    const f32x4 zf = {0.f, 0.f, 0.f, 0.f};
#pragma unroll
    for (int n = 0; n < 4; ++n) acc[n] = zf;

    for (int k0 = 0; k0 < HDIM; k0 += KC) {
        __syncthreads();
        // stage x tile [32][96] fp32 -> bf16 LDS  (3 float4 / thread)
#pragma unroll
        for (int i = 0; i < (TM * KC / 4) / NTHR; ++i) {
            int f   = tid + i * NTHR;
            int row = f / (KC / 4), c4 = f % (KC / 4);
            float4 gx = *((const float4*)(x + (size_t)(tok0 + row) * HDIM + k0) + c4);
            ushort4 b; b.x = f2bf(gx.x); b.y = f2bf(gx.y); b.z = f2bf(gx.z); b.w = f2bf(gx.w);
            *(ushort4*)(xA + row * LDROW + c4 * 8) = b;
        }
        // stage w tile [128][96] fp32 -> bf16 LDS  (12 float4 / thread)
#pragma unroll
        for (int i = 0; i < (EEXP * KC / 4) / NTHR; ++i) {
            int f   = tid + i * NTHR;
            int row = f / (KC / 4), c4 = f % (KC / 4);
            float4 gw = *((const float4*)(w + (size_t)row * HDIM + k0) + c4);
            ushort4 b; b.x = f2bf(gw.x); b.y = f2bf(gw.y); b.z = f2bf(gw.z); b.w = f2bf(gw.w);
            *(ushort4*)(wA + row * LDROW + c4 * 8) = b;
        }
        __syncthreads();
#pragma unroll
        for (int ks = 0; ks < KC / 32; ++ks) {
            bf16x8 af = *(const bf16x8*)(xA + (wt * 16 + r) * LDROW + ks * 64 + g * 16);
#pragma unroll
            for (int n = 0; n < 4; ++n) {
                bf16x8 bfr = *(const bf16x8*)(wA + (we * 64 + n * 16 + r) * LDROW + ks * 64 + g * 16);
                acc[n] = __builtin_amdgcn_mfma_f32_16x16x32_bf16(af, bfr, acc[n], 0, 0, 0);
            }
        }
    }
    __syncthreads();

    // logits (+bias) -> LDS [32][LSTR]; D layout: col=lane&15, row=(lane>>4)*4+reg
    float* logitsL = (float*)smem;
#pragma unroll
    for (int n = 0; n < 4; ++n) {
        int e = we * 64 + n * 16 + r;
        float bv = bias[e];
#pragma unroll
        for (int q = 0; q < 4; ++q) {
            int m = wt * 16 + g * 4 + q;
            logitsL[m * LSTR + e] = acc[n][q] + bv;
        }
    }
    int*    candI = (int*)(smem + CAND_OFF);
    double* candV = (double*)(smem + CANDV_OFF);
    __syncthreads();

    // ---------------- top-8 candidate selection (fp32) -----------------------
    if (tid < TM) {
        float v[8]; int id[8];
#pragma unroll
        for (int j = 0; j < 8; ++j) { v[j] = -3.4e38f; id[j] = 0x7fffffff; }
        for (int e = 0; e < EEXP; ++e) {
            float lv = logitsL[tid * LSTR + e];
            if (lv > v[7]) {
                int j = 7;
                while (j > 0 && v[j - 1] < lv) {
                    v[j] = v[j - 1]; id[j] = id[j - 1]; --j;
                }
                v[j] = lv; id[j] = e;
            }
        }
#pragma unroll
        for (int j = 0; j < 8; ++j) candI[tid * 8 + j] = id[j];
    }
    __syncthreads();

    // ---------------- Phase B: fp64 re-accumulation of 8 candidates ----------
    const int tt = tid >> 3;            // token 0..31
    const int cc = tid & 7;             // candidate 0..7
    const int ce = candI[tt * 8 + cc];
    const float* wp = w + (size_t)ce * HDIM;
    float* xB = (float*)smem;           // [32][XBSTR] fp32
    double accd = 0.0;
    for (int k0 = 0; k0 < HDIM; k0 += KC) {
        __syncthreads();
#pragma unroll
        for (int i = 0; i < (TM * KC / 4) / NTHR; ++i) {
            int f   = tid + i * NTHR;
            int row = f / (KC / 4), c4 = f % (KC / 4);
            *(float4*)(xB + row * XBSTR + c4 * 4) =
                *((const float4*)(x + (size_t)(tok0 + row) * HDIM + k0) + c4);
        }
        __syncthreads();
#pragma unroll 4
        for (int kk = 0; kk < KC; kk += 4) {
            float4 xv = *(const float4*)(xB + tt * XBSTR + kk);
            float4 wv = *(const float4*)(wp + k0 + kk);
            accd = fma((double)xv.x, (double)wv.x, accd);
            accd = fma((double)xv.y, (double)wv.y, accd);
            accd = fma((double)xv.z, (double)wv.z, accd);
            accd = fma((double)xv.w, (double)wv.w, accd);
        }
    }
    accd += (double)bias[ce];
    candV[tt * 8 + cc] = accd;
    __syncthreads();

    // ---------------- top-4 sort, fp64 softmax, outputs ----------------------
    float* scores = (float*)smem;       // [32][128]
    const float4 z4 = make_float4(0.f, 0.f, 0.f, 0.f);
#pragma unroll
    for (int i = 0; i < (TM * EEXP / 4) / NTHR; ++i)
        ((float4*)scores)[tid + i * NTHR] = z4;
    __syncthreads();

    if (tid < TM) {
        double sv[8]; int sid[8];
#pragma unroll
        for (int c = 0; c < 8; ++c) {
            sv[c]  = candV[tid * 8 + c];
            sid[c] = candI[tid * 8 + c];
        }
        for (int j = 0; j < 4; ++j) {   // stable selection sort, descending
            int b = j;
            for (int c = j + 1; c < 8; ++c)
                if (sv[c] > sv[b] || (sv[c] == sv[b] && sid[c] < sid[b])) b = c;
            double tv = sv[j]; sv[j] = sv[b]; sv[b] = tv;
            int ti = sid[j]; sid[j] = sid[b]; sid[b] = ti;
        }
        double m = sv[0], s = 0.0, ev[4];
#pragma unroll
        for (int j = 0; j < 4; ++j) { ev[j] = exp(sv[j] - m); s += ev[j]; }
        double invs = 1.0 / s;
        float* oidx = out + (size_t)T_TOK * EEXP;
#pragma unroll
        for (int j = 0; j < 4; ++j) {
            oidx[(size_t)(tok0 + tid) * KTOP + j] = (float)sid[j];
            scores[tid * EEXP + sid[j]] = (float)(ev[j] * invs);
        }
    }
    __syncthreads();

    float4* outv = (float4*)(out + (size_t)tok0 * EEXP);
#pragma unroll
    for (int i = 0; i < (TM * EEXP / 4) / NTHR; ++i)
        outv[tid + i * NTHR] = ((float4*)scores)[tid + i * NTHR];
}

extern "C" void kernel_launch(void* const* d_in, const int* in_sizes, int n_in,
                              void* d_out, int out_size, void* d_ws, size_t ws_size,
                              hipStream_t stream) {
    const float* x    = (const float*)d_in[0];
    const float* w    = (const float*)d_in[1];
    const float* bias = (const float*)d_in[2];
    float* out        = (float*)d_out;

    dim3 grid(T_TOK / TM), block(NTHR);
    hipLaunchKernelGGL(router_kernel, grid, block, 0, stream, x, w, bias, out);
}

// Round 4
// 184.969 us; speedup vs baseline: 4.6551x; 2.0994x over previous
//
#include <hip/hip_runtime.h>
#include <math.h>

// GptOssRouter: T=16384, H=2880, E=128, K=4.
// K1: bf16 MFMA GEMM (x@W^T+bias) -> fp32 logits -> top-8 candidate indices
//     (written into the output score rows as scratch; K2 overwrites them).
// K2: one block per token; fp64 re-accumulation of the 8 candidates with
//     coalesced 32-lane dot products, so top-4 ORDER matches the float64
//     numpy reference exactly; fp64 softmax; dense scatter + index output.

#define T_TOK 16384
#define HDIM  2880
#define EEXP  128
#define KTOP  4

// ---------------- Kernel 1 ----------------
#define TM    64            // tokens per block
#define NT1   512           // 8 waves
#define KC    96            // K-chunk (2880 = 30*96)
#define NC4   (KC / 4)      // 24 float4 per row-chunk
#define LDROW 208           // bf16 LDS row stride in BYTES (104 bf16, 13*16B)
#define LSTR  132           // logits LDS stride (floats)

#define XA_OFF   0
#define WA_OFF   (TM * LDROW)                     // 13312
#define SMEM1    (WA_OFF + EEXP * LDROW)          // 39936 bytes

typedef __attribute__((ext_vector_type(8))) short bf16x8;
typedef __attribute__((ext_vector_type(4))) float f32x4;

static __device__ __forceinline__ unsigned short f2bf(float f) {
    union { float f; unsigned int u; } v; v.f = f;
    unsigned int u = v.u;
    return (unsigned short)((u + 0x7fffu + ((u >> 16) & 1u)) >> 16);  // RNE
}
static __device__ __forceinline__ ushort4 cvt4(float4 g) {
    ushort4 b; b.x = f2bf(g.x); b.y = f2bf(g.y); b.z = f2bf(g.z); b.w = f2bf(g.w);
    return b;
}

__global__ __launch_bounds__(NT1, 4) void router_gemm_top8(
    const float* __restrict__ x, const float* __restrict__ w,
    const float* __restrict__ bias, float* __restrict__ out)
{
    __shared__ char smem[SMEM1];
    const int tid  = threadIdx.x;
    const int tok0 = blockIdx.x * TM;
    const int lane = tid & 63;
    const int wv   = tid >> 6;
    const int wt   = wv & 3;            // token 16-row group (0..3)
    const int we   = wv >> 2;           // expert 64-col group (0..1)
    const int r    = lane & 15;
    const int g    = lane >> 4;

    char* xA = smem + XA_OFF;
    char* wA = smem + WA_OFF;

    f32x4 acc[4];
    const f32x4 zf = {0.f, 0.f, 0.f, 0.f};
#pragma unroll
    for (int n = 0; n < 4; ++n) acc[n] = zf;

    // register prefetch buffers: x 3 float4, w 6 float4 per thread
    float4 px[3], pw[6];
    int xrow[3], xc4[3], wrow[6], wc4[6];
#pragma unroll
    for (int i = 0; i < 3; ++i) {
        int f = tid + i * NT1; xrow[i] = f / NC4; xc4[i] = f % NC4;
    }
#pragma unroll
    for (int i = 0; i < 6; ++i) {
        int f = tid + i * NT1; wrow[i] = f / NC4; wc4[i] = f % NC4;
    }

#pragma unroll
    for (int i = 0; i < 3; ++i)
        px[i] = *((const float4*)(x + (size_t)(tok0 + xrow[i]) * HDIM) + xc4[i]);
#pragma unroll
    for (int i = 0; i < 6; ++i)
        pw[i] = *((const float4*)(w + (size_t)wrow[i] * HDIM) + wc4[i]);

    for (int c = 0; c < HDIM / KC; ++c) {
        __syncthreads();                 // previous chunk's MFMA reads done
#pragma unroll
        for (int i = 0; i < 3; ++i)
            *(ushort4*)(xA + xrow[i] * LDROW + xc4[i] * 8) = cvt4(px[i]);
#pragma unroll
        for (int i = 0; i < 6; ++i)
            *(ushort4*)(wA + wrow[i] * LDROW + wc4[i] * 8) = cvt4(pw[i]);
        __syncthreads();
        if (c + 1 < HDIM / KC) {         // prefetch next chunk during MFMA
            int k0 = (c + 1) * KC;
#pragma unroll
            for (int i = 0; i < 3; ++i)
                px[i] = *((const float4*)(x + (size_t)(tok0 + xrow[i]) * HDIM + k0) + xc4[i]);
#pragma unroll
            for (int i = 0; i < 6; ++i)
                pw[i] = *((const float4*)(w + (size_t)wrow[i] * HDIM + k0) + wc4[i]);
        }
#pragma unroll
        for (int ks = 0; ks < KC / 32; ++ks) {
            bf16x8 af = *(const bf16x8*)(xA + (wt * 16 + r) * LDROW + ks * 64 + g * 16);
#pragma unroll
            for (int n = 0; n < 4; ++n) {
                bf16x8 bfr = *(const bf16x8*)(wA + (we * 64 + n * 16 + r) * LDROW + ks * 64 + g * 16);
                acc[n] = __builtin_amdgcn_mfma_f32_16x16x32_bf16(af, bfr, acc[n], 0, 0, 0);
            }
        }
    }
    __syncthreads();

    // logits (+bias) -> LDS [64][LSTR]; D layout: col=lane&15, row=(lane>>4)*4+reg
    float* logitsL = (float*)smem;
#pragma unroll
    for (int n = 0; n < 4; ++n) {
        int e = we * 64 + n * 16 + r;
        float bv = bias[e];
#pragma unroll
        for (int q = 0; q < 4; ++q) {
            int m = wt * 16 + g * 4 + q;
            logitsL[m * LSTR + e] = acc[n][q] + bv;
        }
    }
    __syncthreads();

    // top-8 candidate selection (fp32): thread t scans token t's 128 logits.
    // Candidates written into this token's OUTPUT SCORE ROW (K2 reads then
    // overwrites them) -- avoids any d_ws dependency.
    if (tid < TM) {
        float v[8]; int id[8];
#pragma unroll
        for (int j = 0; j < 8; ++j) { v[j] = -3.4e38f; id[j] = 0x7fffffff; }
        for (int e = 0; e < EEXP; ++e) {
            float lv = logitsL[tid * LSTR + e];
            if (lv > v[7]) {
                int j = 7;
                while (j > 0 && v[j - 1] < lv) {
                    v[j] = v[j - 1]; id[j] = id[j - 1]; --j;
                }
                v[j] = lv; id[j] = e;
            }
        }
        int* crow = (int*)(out + (size_t)(tok0 + tid) * EEXP);
#pragma unroll
        for (int j = 0; j < 8; ++j) crow[j] = id[j];
    }
}

// ---------------- Kernel 2 ----------------
#define NT2 256

__global__ __launch_bounds__(NT2) void router_rescore(
    const float* __restrict__ x, const float* __restrict__ w,
    const float* __restrict__ bias, float* __restrict__ out)
{
    __shared__ float  xl[HDIM];         // 11520 B
    __shared__ int    ci[8];
    __shared__ double cv[8];
    __shared__ float  sr[EEXP];

    const int t   = blockIdx.x;
    const int tid = threadIdx.x;

    // stage x row (720 float4)
    const float4* xr4 = (const float4*)(x + (size_t)t * HDIM);
#pragma unroll
    for (int i = 0; i < 3; ++i) {
        int idx = tid + i * NT2;
        if (idx < HDIM / 4) ((float4*)xl)[idx] = xr4[idx];
    }
    if (tid < 8) ci[tid] = ((const int*)(out + (size_t)t * EEXP))[tid];
    __syncthreads();

    // 32 lanes per candidate: coalesced w reads, fp64 accumulate
    const int c  = tid >> 5;            // candidate 0..7
    const int s  = tid & 31;            // sub-lane
    const int ce = ci[c];
    const float4* wr4 = (const float4*)(w + (size_t)ce * HDIM);
    double acc = 0.0;
#pragma unroll 2
    for (int i = 0; i < 22; ++i) {      // 22*32 = 704 float4
        int fi = s + i * 32;
        float4 xv = ((float4*)xl)[fi];
        float4 wv = wr4[fi];
        acc = fma((double)xv.x, (double)wv.x, acc);
        acc = fma((double)xv.y, (double)wv.y, acc);
        acc = fma((double)xv.z, (double)wv.z, acc);
        acc = fma((double)xv.w, (double)wv.w, acc);
    }
    if (s < 16) {                       // tail: remaining 16 float4
        int fi = 704 + s;
        float4 xv = ((float4*)xl)[fi];
        float4 wv = wr4[fi];
        acc = fma((double)xv.x, (double)wv.x, acc);
        acc = fma((double)xv.y, (double)wv.y, acc);
        acc = fma((double)xv.z, (double)wv.z, acc);
        acc = fma((double)xv.w, (double)wv.w, acc);
    }
#pragma unroll
    for (int off = 16; off > 0; off >>= 1)
        acc += __shfl_xor(acc, off);    // xor-butterfly closed within 32-lane group
    if (s == 0) cv[c] = acc + (double)bias[ce];
    __syncthreads();

    if (tid < 32) ((float4*)sr)[tid] = make_float4(0.f, 0.f, 0.f, 0.f);
    __syncthreads();

    if (tid == 0) {
        double sv[8]; int sid[8];
#pragma unroll
        for (int j = 0; j < 8; ++j) { sv[j] = cv[j]; sid[j] = ci[j]; }
        for (int j = 0; j < 4; ++j) {   // stable selection sort, descending
            int b = j;
            for (int k = j + 1; k < 8; ++k)
                if (sv[k] > sv[b] || (sv[k] == sv[b] && sid[k] < sid[b])) b = k;
            double tv = sv[j]; sv[j] = sv[b]; sv[b] = tv;
            int ti = sid[j]; sid[j] = sid[b]; sid[b] = ti;
        }
        double m = sv[0], ssum = 0.0, ev[4];
#pragma unroll
        for (int j = 0; j < 4; ++j) { ev[j] = exp(sv[j] - m); ssum += ev[j]; }
        double invs = 1.0 / ssum;
        float* oidx = out + (size_t)T_TOK * EEXP;
#pragma unroll
        for (int j = 0; j < 4; ++j) {
            oidx[(size_t)t * KTOP + j] = (float)sid[j];
            sr[sid[j]] = (float)(ev[j] * invs);
        }
    }
    __syncthreads();

    float4* orow = (float4*)(out + (size_t)t * EEXP);
    if (tid < 32) orow[tid] = ((float4*)sr)[tid];
}

extern "C" void kernel_launch(void* const* d_in, const int* in_sizes, int n_in,
                              void* d_out, int out_size, void* d_ws, size_t ws_size,
                              hipStream_t stream) {
    const float* x    = (const float*)d_in[0];
    const float* w    = (const float*)d_in[1];
    const float* bias = (const float*)d_in[2];
    float* out        = (float*)d_out;

    hipLaunchKernelGGL(router_gemm_top8, dim3(T_TOK / TM), dim3(NT1), 0, stream,
                       x, w, bias, out);
    hipLaunchKernelGGL(router_rescore, dim3(T_TOK), dim3(NT2), 0, stream,
                       x, w, bias, out);
}

// Round 5
// 175.511 us; speedup vs baseline: 4.9060x; 1.0539x over previous
//
#include <hip/hip_runtime.h>
#include <math.h>

// GptOssRouter: T=16384, H=2880, E=128, K=4.
// K1: bf16 MFMA GEMM (x@W^T+bias) over 1024 blocks (32tok x 64exp each),
//     double-buffered LDS, 1 barrier/chunk, reg-prefetch issue-early.
//     Raw fp32 logits written into the output score rows (scratch).
// K2: per token: wave-parallel top-8 from the logit row, fp64 re-accumulation
//     of the 8 candidates (coalesced 32-lane dots) so the top-4 ORDER matches
//     the float64 numpy reference; fp64 softmax; overwrite row + idx output.

#define T_TOK 16384
#define HDIM  2880
#define EEXP  128
#define KTOP  4

// ---------------- Kernel 1 ----------------
#define TM    32            // tokens per block
#define EN    64            // experts per block
#define NT1   256           // 4 waves
#define KC    64            // K-chunk (2880 = 45*64)
#define NC4   (KC / 4)      // 16 float4 per row-chunk
#define NCH   (HDIM / KC)   // 45
#define LDROW 144           // bf16 LDS row stride in BYTES (64 bf16 = 128B + 16 pad)
#define ROWS  (TM + EN)     // 96 rows per buffer (32 x + 64 w)
#define BUFB  (ROWS * LDROW)// 13824 B per buffer
#define NPF   6             // float4 staged per thread per chunk (96*16/256)

typedef __attribute__((ext_vector_type(8))) short bf16x8;
typedef __attribute__((ext_vector_type(4))) float f32x4;

// pack trunc-bf16(a), trunc-bf16(b) into one u32 (a in low half) via v_perm
static __device__ __forceinline__ unsigned pack2bf(float a, float b) {
    union { float f; unsigned u; } ua, ub; ua.f = a; ub.f = b;
    return __builtin_amdgcn_perm(ub.u, ua.u, 0x07060302u);
}

__global__ __launch_bounds__(NT1, 4) void router_gemm(
    const float* __restrict__ x, const float* __restrict__ w,
    const float* __restrict__ bias, float* __restrict__ out)
{
    __shared__ char smem[2 * BUFB];     // 27648 B
    const int tid = threadIdx.x;
    const int blk = blockIdx.x;
    // XCD-paired swizzle: blocks round-robin XCDs; give each XCD a contiguous
    // token range and keep the two expert-halves of a token tile adjacent.
    const int xcd = blk & 7;
    const int j   = blk >> 3;           // 0..127 within XCD
    const int be  = j & 1;              // expert half
    const int p   = xcd * 64 + (j >> 1);// token tile 0..511
    const int tok0 = p * TM;
    const int e0   = be * EN;

    const int lane = tid & 63;
    const int wv   = tid >> 6;
    const int wt   = wv & 1;            // token 16-row group
    const int wn   = wv >> 1;           // expert 32-col group
    const int r    = lane & 15;
    const int g    = lane >> 4;

    // staging map: 96 rows x 16 float4 = 1536 float4, 6 per thread
    const float* sptr[NPF];
    int soff[NPF];
#pragma unroll
    for (int i = 0; i < NPF; ++i) {
        int f = tid + i * NT1;
        int row = f >> 4, c4 = f & 15;
        soff[i] = row * LDROW + c4 * 8;
        sptr[i] = (row < TM) ? (x + (size_t)(tok0 + row) * HDIM + c4 * 4)
                             : (w + (size_t)(e0 + row - TM) * HDIM + c4 * 4);
    }

    f32x4 acc[2];
    const f32x4 zf = {0.f, 0.f, 0.f, 0.f};
    acc[0] = zf; acc[1] = zf;

    float4 pf[NPF];
    // prologue: chunk 0 -> regs -> buf0
#pragma unroll
    for (int i = 0; i < NPF; ++i) pf[i] = *(const float4*)sptr[i];
#pragma unroll
    for (int i = 0; i < NPF; ++i) {
        uint2 c; c.x = pack2bf(pf[i].x, pf[i].y); c.y = pack2bf(pf[i].z, pf[i].w);
        *(uint2*)(smem + soff[i]) = c;
    }
    __syncthreads();

    for (int c = 0; c < NCH; ++c) {
        char* cb = smem + (c & 1) * BUFB;        // compute buffer
        char* sb = smem + ((c & 1) ^ 1) * BUFB;  // stage buffer
        const bool more = (c + 1 < NCH);
        if (more) {
            int koff = (c + 1) * KC;
#pragma unroll
            for (int i = 0; i < NPF; ++i)
                pf[i] = *(const float4*)(sptr[i] + koff);
        }
#pragma unroll
        for (int ks = 0; ks < KC / 32; ++ks) {
            bf16x8 af = *(const bf16x8*)(cb + (wt * 16 + r) * LDROW + ks * 64 + g * 16);
#pragma unroll
            for (int n = 0; n < 2; ++n) {
                bf16x8 bfr = *(const bf16x8*)(cb + (TM + wn * 32 + n * 16 + r) * LDROW + ks * 64 + g * 16);
                acc[n] = __builtin_amdgcn_mfma_f32_16x16x32_bf16(af, bfr, acc[n], 0, 0, 0);
            }
        }
        if (more) {
#pragma unroll
            for (int i = 0; i < NPF; ++i) {
                uint2 cv; cv.x = pack2bf(pf[i].x, pf[i].y); cv.y = pack2bf(pf[i].z, pf[i].w);
                *(uint2*)(sb + soff[i]) = cv;
            }
        }
        __syncthreads();
    }

    // epilogue: logits(+bias) -> out score rows (scratch for K2)
    // D layout: col(lane&15)=expert-frag, row=(lane>>4)*4+reg = token
#pragma unroll
    for (int n = 0; n < 2; ++n) {
        int e = e0 + wn * 32 + n * 16 + r;
        float bv = bias[e];
#pragma unroll
        for (int q = 0; q < 4; ++q) {
            int m = wt * 16 + g * 4 + q;
            out[(size_t)(tok0 + m) * EEXP + e] = acc[n][q] + bv;
        }
    }
}

// ---------------- Kernel 2 ----------------
#define NT2 256

__global__ __launch_bounds__(NT2) void router_rescore(
    const float* __restrict__ x, const float* __restrict__ w,
    const float* __restrict__ bias, float* __restrict__ out)
{
    __shared__ float  xl[HDIM];         // 11520 B
    __shared__ int    ci[8];
    __shared__ double cv[8];
    __shared__ float  sr[EEXP];

    const int t   = blockIdx.x;
    const int tid = threadIdx.x;

    // stage x row (720 float4)
    const float4* xr4 = (const float4*)(x + (size_t)t * HDIM);
    for (int i = tid; i < HDIM / 4; i += NT2) ((float4*)xl)[i] = xr4[i];

    // wave 0: top-8 argmax over the 128 logits K1 left in the out row
    if (tid < 64) {
        float v0 = out[(size_t)t * EEXP + tid];
        float v1 = out[(size_t)t * EEXP + 64 + tid];
#pragma unroll
        for (int jj = 0; jj < 8; ++jj) {
            float v; int idx;
            if (v0 >= v1) { v = v0; idx = tid; }        // tie -> lower index
            else          { v = v1; idx = tid + 64; }
#pragma unroll
            for (int off = 32; off; off >>= 1) {
                float ov = __shfl_xor(v, off);
                int   oi = __shfl_xor(idx, off);
                if (ov > v || (ov == v && oi < idx)) { v = ov; idx = oi; }
            }
            if (tid == 0) ci[jj] = idx;
            if (idx == tid)      v0 = -3.4e38f;
            if (idx == tid + 64) v1 = -3.4e38f;
        }
    }
    __syncthreads();

    // 32 lanes per candidate: coalesced w reads, fp64 accumulate
    const int c  = tid >> 5;            // candidate 0..7
    const int s  = tid & 31;            // sub-lane
    const int ce = ci[c];
    const float4* wr4 = (const float4*)(w + (size_t)ce * HDIM);
    double acc = 0.0;
#pragma unroll 2
    for (int i = 0; i < 22; ++i) {      // 22*32 = 704 float4
        int fi = s + i * 32;
        float4 xv = ((float4*)xl)[fi];
        float4 wv = wr4[fi];
        acc = fma((double)xv.x, (double)wv.x, acc);
        acc = fma((double)xv.y, (double)wv.y, acc);
        acc = fma((double)xv.z, (double)wv.z, acc);
        acc = fma((double)xv.w, (double)wv.w, acc);
    }
    if (s < 16) {                       // tail: remaining 16 float4
        int fi = 704 + s;
        float4 xv = ((float4*)xl)[fi];
        float4 wv = wr4[fi];
        acc = fma((double)xv.x, (double)wv.x, acc);
        acc = fma((double)xv.y, (double)wv.y, acc);
        acc = fma((double)xv.z, (double)wv.z, acc);
        acc = fma((double)xv.w, (double)wv.w, acc);
    }
#pragma unroll
    for (int off = 16; off > 0; off >>= 1)
        acc += __shfl_xor(acc, off);    // butterfly closed within 32-lane group
    if (s == 0) cv[c] = acc + (double)bias[ce];
    __syncthreads();

    if (tid < 32) ((float4*)sr)[tid] = make_float4(0.f, 0.f, 0.f, 0.f);
    __syncthreads();

    if (tid == 0) {
        double sv[8]; int sid[8];
#pragma unroll
        for (int jj = 0; jj < 8; ++jj) { sv[jj] = cv[jj]; sid[jj] = ci[jj]; }
        for (int jj = 0; jj < 4; ++jj) {   // stable selection sort, descending
            int b = jj;
            for (int k = jj + 1; k < 8; ++k)
                if (sv[k] > sv[b] || (sv[k] == sv[b] && sid[k] < sid[b])) b = k;
            double tv = sv[jj]; sv[jj] = sv[b]; sv[b] = tv;
            int ti = sid[jj]; sid[jj] = sid[b]; sid[b] = ti;
        }
        double m = sv[0], ssum = 0.0, ev[4];
#pragma unroll
        for (int jj = 0; jj < 4; ++jj) { ev[jj] = exp(sv[jj] - m); ssum += ev[jj]; }
        double invs = 1.0 / ssum;
        float* oidx = out + (size_t)T_TOK * EEXP;
#pragma unroll
        for (int jj = 0; jj < 4; ++jj) {
            oidx[(size_t)t * KTOP + jj] = (float)sid[jj];
            sr[sid[jj]] = (float)(ev[jj] * invs);
        }
    }
    __syncthreads();

    float4* orow = (float4*)(out + (size_t)t * EEXP);
    if (tid < 32) orow[tid] = ((float4*)sr)[tid];
}

extern "C" void kernel_launch(void* const* d_in, const int* in_sizes, int n_in,
                              void* d_out, int out_size, void* d_ws, size_t ws_size,
                              hipStream_t stream) {
    const float* x    = (const float*)d_in[0];
    const float* w    = (const float*)d_in[1];
    const float* bias = (const float*)d_in[2];
    float* out        = (float*)d_out;

    hipLaunchKernelGGL(router_gemm, dim3((T_TOK / TM) * (EEXP / EN)), dim3(NT1),
                       0, stream, x, w, bias, out);
    hipLaunchKernelGGL(router_rescore, dim3(T_TOK), dim3(NT2), 0, stream,
                       x, w, bias, out);
}

// Round 6
// 175.115 us; speedup vs baseline: 4.9170x; 1.0023x over previous
//
#include <hip/hip_runtime.h>
#include <math.h>

// GptOssRouter: T=16384, H=2880, E=128, K=4.
// K1: bf16 MFMA GEMM (x@W^T+bias) over 1024 blocks (32tok x 64exp each),
//     double-buffered LDS, 1 barrier/chunk, reg-prefetch issue-early.
//     Raw fp32 logits written into the output score rows (scratch).
// K2: per token: wave-parallel top-8 from the logit row, fp64 re-accumulation
//     of the 8 candidates (coalesced 32-lane dots, 4 independent accumulators
//     to break the fp64 FMA dependency chain) so the top-4 ORDER matches the
//     float64 numpy reference; fp64 softmax; overwrite row + idx output.

#define T_TOK 16384
#define HDIM  2880
#define EEXP  128
#define KTOP  4

// ---------------- Kernel 1 ----------------
#define TM    32            // tokens per block
#define EN    64            // experts per block
#define NT1   256           // 4 waves
#define KC    64            // K-chunk (2880 = 45*64)
#define NC4   (KC / 4)      // 16 float4 per row-chunk
#define NCH   (HDIM / KC)   // 45
#define LDROW 144           // bf16 LDS row stride in BYTES (64 bf16 = 128B + 16 pad)
#define ROWS  (TM + EN)     // 96 rows per buffer (32 x + 64 w)
#define BUFB  (ROWS * LDROW)// 13824 B per buffer
#define NPF   6             // float4 staged per thread per chunk (96*16/256)

typedef __attribute__((ext_vector_type(8))) short bf16x8;
typedef __attribute__((ext_vector_type(4))) float f32x4;

// pack trunc-bf16(a), trunc-bf16(b) into one u32 (a in low half) via v_perm
static __device__ __forceinline__ unsigned pack2bf(float a, float b) {
    union { float f; unsigned u; } ua, ub; ua.f = a; ub.f = b;
    return __builtin_amdgcn_perm(ub.u, ua.u, 0x07060302u);
}

__global__ __launch_bounds__(NT1, 4) void router_gemm(
    const float* __restrict__ x, const float* __restrict__ w,
    const float* __restrict__ bias, float* __restrict__ out)
{
    __shared__ char smem[2 * BUFB];     // 27648 B
    const int tid = threadIdx.x;
    const int blk = blockIdx.x;
    const int xcd = blk & 7;
    const int j   = blk >> 3;           // 0..127 within XCD
    const int be  = j & 1;              // expert half
    const int p   = xcd * 64 + (j >> 1);// token tile 0..511
    const int tok0 = p * TM;
    const int e0   = be * EN;

    const int lane = tid & 63;
    const int wv   = tid >> 6;
    const int wt   = wv & 1;            // token 16-row group
    const int wn   = wv >> 1;           // expert 32-col group
    const int r    = lane & 15;
    const int g    = lane >> 4;

    // staging map: 96 rows x 16 float4 = 1536 float4, 6 per thread
    const float* sptr[NPF];
    int soff[NPF];
#pragma unroll
    for (int i = 0; i < NPF; ++i) {
        int f = tid + i * NT1;
        int row = f >> 4, c4 = f & 15;
        soff[i] = row * LDROW + c4 * 8;
        sptr[i] = (row < TM) ? (x + (size_t)(tok0 + row) * HDIM + c4 * 4)
                             : (w + (size_t)(e0 + row - TM) * HDIM + c4 * 4);
    }

    f32x4 acc[2];
    const f32x4 zf = {0.f, 0.f, 0.f, 0.f};
    acc[0] = zf; acc[1] = zf;

    float4 pf[NPF];
    // prologue: chunk 0 -> regs -> buf0
#pragma unroll
    for (int i = 0; i < NPF; ++i) pf[i] = *(const float4*)sptr[i];
#pragma unroll
    for (int i = 0; i < NPF; ++i) {
        uint2 c; c.x = pack2bf(pf[i].x, pf[i].y); c.y = pack2bf(pf[i].z, pf[i].w);
        *(uint2*)(smem + soff[i]) = c;
    }
    __syncthreads();

    for (int c = 0; c < NCH; ++c) {
        char* cb = smem + (c & 1) * BUFB;        // compute buffer
        char* sb = smem + ((c & 1) ^ 1) * BUFB;  // stage buffer
        const bool more = (c + 1 < NCH);
        if (more) {
            int koff = (c + 1) * KC;
#pragma unroll
            for (int i = 0; i < NPF; ++i)
                pf[i] = *(const float4*)(sptr[i] + koff);
        }
#pragma unroll
        for (int ks = 0; ks < KC / 32; ++ks) {
            bf16x8 af = *(const bf16x8*)(cb + (wt * 16 + r) * LDROW + ks * 64 + g * 16);
#pragma unroll
            for (int n = 0; n < 2; ++n) {
                bf16x8 bfr = *(const bf16x8*)(cb + (TM + wn * 32 + n * 16 + r) * LDROW + ks * 64 + g * 16);
                acc[n] = __builtin_amdgcn_mfma_f32_16x16x32_bf16(af, bfr, acc[n], 0, 0, 0);
            }
        }
        if (more) {
#pragma unroll
            for (int i = 0; i < NPF; ++i) {
                uint2 cv; cv.x = pack2bf(pf[i].x, pf[i].y); cv.y = pack2bf(pf[i].z, pf[i].w);
                *(uint2*)(sb + soff[i]) = cv;
            }
        }
        __syncthreads();
    }

    // epilogue: logits(+bias) -> out score rows (scratch for K2)
#pragma unroll
    for (int n = 0; n < 2; ++n) {
        int e = e0 + wn * 32 + n * 16 + r;
        float bv = bias[e];
#pragma unroll
        for (int q = 0; q < 4; ++q) {
            int m = wt * 16 + g * 4 + q;
            out[(size_t)(tok0 + m) * EEXP + e] = acc[n][q] + bv;
        }
    }
}

// ---------------- Kernel 2 ----------------
#define NT2 256

__global__ __launch_bounds__(NT2) void router_rescore(
    const float* __restrict__ x, const float* __restrict__ w,
    const float* __restrict__ bias, float* __restrict__ out)
{
    __shared__ float  xl[HDIM];         // 11520 B
    __shared__ int    ci[8];
    __shared__ double cv[8];
    __shared__ float  sr[EEXP];

    const int t   = blockIdx.x;
    const int tid = threadIdx.x;

    // stage x row (720 float4)
    const float4* xr4 = (const float4*)(x + (size_t)t * HDIM);
    for (int i = tid; i < HDIM / 4; i += NT2) ((float4*)xl)[i] = xr4[i];

    // wave 0: top-8 argmax over the 128 logits K1 left in the out row
    if (tid < 64) {
        float v0 = out[(size_t)t * EEXP + tid];
        float v1 = out[(size_t)t * EEXP + 64 + tid];
#pragma unroll
        for (int jj = 0; jj < 8; ++jj) {
            float v; int idx;
            if (v0 >= v1) { v = v0; idx = tid; }        // tie -> lower index
            else          { v = v1; idx = tid + 64; }
#pragma unroll
            for (int off = 32; off; off >>= 1) {
                float ov = __shfl_xor(v, off);
                int   oi = __shfl_xor(idx, off);
                if (ov > v || (ov == v && oi < idx)) { v = ov; idx = oi; }
            }
            if (tid == 0) ci[jj] = idx;
            if (idx == tid)      v0 = -3.4e38f;
            if (idx == tid + 64) v1 = -3.4e38f;
        }
    }
    __syncthreads();

    // 32 lanes per candidate: coalesced w reads; 4 independent fp64
    // accumulators break the FMA dependency chain (90 -> 22 deep, 4-way ILP).
    const int c  = tid >> 5;            // candidate 0..7
    const int s  = tid & 31;            // sub-lane
    const int ce = ci[c];
    const float4* wr4 = (const float4*)(w + (size_t)ce * HDIM);
    const float4* xl4 = (const float4*)xl;
    double ax = 0.0, ay = 0.0, az = 0.0, aw = 0.0;
#pragma unroll 2
    for (int i = 0; i < 22; ++i) {      // 22*32 = 704 float4
        int fi = s + i * 32;
        float4 xv = xl4[fi];
        float4 wv = wr4[fi];
        ax = fma((double)xv.x, (double)wv.x, ax);
        ay = fma((double)xv.y, (double)wv.y, ay);
        az = fma((double)xv.z, (double)wv.z, az);
        aw = fma((double)xv.w, (double)wv.w, aw);
    }
    if (s < 16) {                       // tail: remaining 16 float4
        int fi = 704 + s;
        float4 xv = xl4[fi];
        float4 wv = wr4[fi];
        ax = fma((double)xv.x, (double)wv.x, ax);
        ay = fma((double)xv.y, (double)wv.y, ay);
        az = fma((double)xv.z, (double)wv.z, az);
        aw = fma((double)xv.w, (double)wv.w, aw);
    }
    double acc = (ax + az) + (ay + aw);
#pragma unroll
    for (int off = 16; off > 0; off >>= 1)
        acc += __shfl_xor(acc, off);    // butterfly closed within 32-lane group
    if (s == 0) cv[c] = acc + (double)bias[ce];
    __syncthreads();

    if (tid < 32) ((float4*)sr)[tid] = make_float4(0.f, 0.f, 0.f, 0.f);
    __syncthreads();

    if (tid == 0) {
        double sv[8]; int sid[8];
#pragma unroll
        for (int jj = 0; jj < 8; ++jj) { sv[jj] = cv[jj]; sid[jj] = ci[jj]; }
        for (int jj = 0; jj < 4; ++jj) {   // stable selection sort, descending
            int b = jj;
            for (int k = jj + 1; k < 8; ++k)
                if (sv[k] > sv[b] || (sv[k] == sv[b] && sid[k] < sid[b])) b = k;
            double tv = sv[jj]; sv[jj] = sv[b]; sv[b] = tv;
            int ti = sid[jj]; sid[jj] = sid[b]; sid[b] = ti;
        }
        double m = sv[0], ssum = 0.0, ev[4];
#pragma unroll
        for (int jj = 0; jj < 4; ++jj) { ev[jj] = exp(sv[jj] - m); ssum += ev[jj]; }
        double invs = 1.0 / ssum;
        float* oidx = out + (size_t)T_TOK * EEXP;
#pragma unroll
        for (int jj = 0; jj < 4; ++jj) {
            oidx[(size_t)t * KTOP + jj] = (float)sid[jj];
            sr[sid[jj]] = (float)(ev[jj] * invs);
        }
    }
    __syncthreads();

    float4* orow = (float4*)(out + (size_t)t * EEXP);
    if (tid < 32) orow[tid] = ((float4*)sr)[tid];
}

extern "C" void kernel_launch(void* const* d_in, const int* in_sizes, int n_in,
                              void* d_out, int out_size, void* d_ws, size_t ws_size,
                              hipStream_t stream) {
    const float* x    = (const float*)d_in[0];
    const float* w    = (const float*)d_in[1];
    const float* bias = (const float*)d_in[2];
    float* out        = (float*)d_out;

    hipLaunchKernelGGL(router_gemm, dim3((T_TOK / TM) * (EEXP / EN)), dim3(NT1),
                       0, stream, x, w, bias, out);
    hipLaunchKernelGGL(router_rescore, dim3(T_TOK), dim3(NT2), 0, stream,
                       x, w, bias, out);
}